// Round 5
// baseline (249.616 us; speedup 1.0000x reference)
//
#include <hip/hip_runtime.h>

#define B_ 2
#define N_ 10000
#define E_ 150000
#define C_ 256
#define M_EDGE (B_*E_)   // 300000
#define M_NODE (B_*N_)   // 20000
#define ED_CAP (M_EDGE + 3*M_NODE + 64)   // padded CSR capacity + tail slack
#define NC_CAP ((M_EDGE + 3*M_NODE)/4 + 4)
#define EPS_ 1e-5f

typedef unsigned short u16;
typedef unsigned int   u32;
typedef __attribute__((ext_vector_type(8))) __bf16 bf16x8;
typedef __attribute__((ext_vector_type(4))) float  f32x4;
typedef _Float16 h2 __attribute__((ext_vector_type(2)));

__device__ __forceinline__ u16 f2bf(float x) {
  union { float f; u32 u; } v; v.f = x;
  u32 r = v.u + 0x7FFFu + ((v.u >> 16) & 1u);   // RNE
  return (u16)(r >> 16);
}
__device__ __forceinline__ float bf2f(u16 x) {
  union { u32 u; float f; } v; v.u = ((u32)x) << 16; return v.f;
}
__device__ __forceinline__ u16 f2h(float x) {
  _Float16 h = (_Float16)x;
  union { _Float16 h; u16 u; } v; v.h = h; return v.u;
}
__device__ __forceinline__ h2 u2h2(u32 x) {
  union { u32 u; h2 h; } v; v.u = x; return v.h;
}

__device__ __forceinline__ void async16(void* lds, const void* g) {
  __builtin_amdgcn_global_load_lds(
      (const __attribute__((address_space(1))) void*)g,
      (__attribute__((address_space(3))) void*)lds, 16, 0, 0);
}

// ---------------- init: zero counts/stats + agg sentinels ----------------
// grid = M_NODE blocks of 256: block=node, thread=channel
__global__ void k_init(int* __restrict__ counts, float* __restrict__ stats,
                       const float* __restrict__ ge, int* __restrict__ agg) {
  int c = threadIdx.x;
  int n = blockIdx.x;
  int i = n * 256 + c;
  if (i < M_NODE) counts[i] = 0;
  if (i < 1024) stats[i] = 0.f;
  // sentinel: max-channels -1.0f, min-channels +inf (int-punned order for y>=0)
  agg[(size_t)n * C_ + c] = (ge[c] >= 0.f) ? (int)0xBF800000u : 0x7F800000;
}

// ---------------- features [B][C][N] f32 -> vf [B][N][C] bf16 ----------------
__global__ void k_transpose_feat(const float* __restrict__ f, u16* __restrict__ vf) {
  __shared__ float tile[32][33];
  int tx = threadIdx.x & 31, ty = threadIdx.x >> 5;
  int b = blockIdx.z, c0 = blockIdx.y * 32, n0 = blockIdx.x * 32;
  #pragma unroll
  for (int i = 0; i < 4; i++) {
    int c = c0 + ty + i*8, n = n0 + tx;
    tile[ty + i*8][tx] = (n < N_) ? f[((size_t)(b*C_ + c))*N_ + n] : 0.f;
  }
  __syncthreads();
  #pragma unroll
  for (int i = 0; i < 4; i++) {
    int n = n0 + ty + i*8, c = c0 + tx;
    if (n < N_) vf[((size_t)(b*N_ + n))*C_ + c] = f2bf(tile[tx][ty + i*8]);
  }
}

// ---------------- W_e[0:256][:], W_u -> transposed bf16 [Cout][K] ----------------
__global__ void k_transpose_w(const float* __restrict__ We, const float* __restrict__ Wu,
                              u16* __restrict__ WeT, u16* __restrict__ WuT) {
  __shared__ float tile[32][33];
  const float* src = blockIdx.z ? Wu : We;
  u16* dst = blockIdx.z ? WuT : WeT;
  int tx = threadIdx.x & 31, ty = threadIdx.x >> 5;
  int r0 = blockIdx.y * 32, c0 = blockIdx.x * 32;
  #pragma unroll
  for (int i = 0; i < 4; i++)
    tile[ty + i*8][tx] = src[(size_t)(r0 + ty + i*8)*C_ + c0 + tx];
  __syncthreads();
  #pragma unroll
  for (int i = 0; i < 4; i++)
    dst[(size_t)(c0 + ty + i*8)*C_ + r0 + tx] = f2bf(tile[tx][ty + i*8]);
}

// ---------------- histogram of dst ----------------
__global__ void k_hist(const int* __restrict__ edges, int* __restrict__ counts) {
  int i = blockIdx.x * 256 + threadIdx.x;
  if (i >= M_EDGE) return;
  int b = (i >= E_) ? 1 : 0;
  int e = i - b * E_;
  int d = edges[(size_t)(b*2 + 1)*E_ + e];
  atomicAdd(&counts[b*N_ + d], 1);
}

// ---------------- exclusive scan of PADDED counts (single block) ----------------
__global__ __launch_bounds__(1024)
void k_scan(const int* __restrict__ counts, int* __restrict__ offs, int* __restrict__ cursor) {
  __shared__ int part[1024];
  int t = threadIdx.x;
  int base = t * 20;
  int vals[20];
  if (t < 1000) {
    #pragma unroll
    for (int j = 0; j < 5; j++)
      *(int4*)&vals[j*4] = *(const int4*)&counts[base + j*4];
  } else {
    #pragma unroll
    for (int i = 0; i < 20; i++) vals[i] = 0;
  }
  int local[20];
  int s = 0;
  #pragma unroll
  for (int i = 0; i < 20; i++) {
    int pv = (vals[i] + 3) & ~3;          // pad each node to multiple of 4
    local[i] = s; s += pv;
  }
  part[t] = s;
  __syncthreads();
  for (int d = 1; d < 1024; d <<= 1) {
    int v = (t >= d) ? part[t - d] : 0;
    __syncthreads();
    part[t] += v;
    __syncthreads();
  }
  int excl = (t == 0) ? 0 : part[t - 1];
  if (t < 1000) {
    #pragma unroll
    for (int j = 0; j < 5; j++) {
      int4 o;
      o.x = excl + local[j*4 + 0];
      o.y = excl + local[j*4 + 1];
      o.z = excl + local[j*4 + 2];
      o.w = excl + local[j*4 + 3];
      *(int4*)&offs[base + j*4]   = o;
      *(int4*)&cursor[base + j*4] = o;
    }
  }
  if (t == 1023) offs[M_NODE] = part[1023];   // total padded size
}

// ---------------- scatter edges into padded CSR slots (packed 8B records) ----------------
// rec.x = f16(dx) | f16(dy)<<16 ; rec.y = f16(dz) | src_node<<16
__global__ void k_scatter(const int* __restrict__ edges, const float* __restrict__ xyz,
                          int* __restrict__ cursor, uint2* __restrict__ ed) {
  int i = blockIdx.x * 256 + threadIdx.x;
  if (i >= M_EDGE) return;
  int b = (i >= E_) ? 1 : 0;
  int e = i - b * E_;
  int s = edges[(size_t)(b*2 + 0)*E_ + e];
  int d = edges[(size_t)(b*2 + 1)*E_ + e];
  const float* ps = xyz + ((size_t)(b*N_ + s))*3;
  const float* pd = xyz + ((size_t)(b*N_ + d))*3;
  int pos = atomicAdd(&cursor[b*N_ + d], 1);
  u32 rx = (u32)f2h(ps[0]-pd[0]) | ((u32)f2h(ps[1]-pd[1]) << 16);
  u32 ry = (u32)f2h(ps[2]-pd[2]) | ((u32)(b*N_ + s) << 16);
  ed[pos] = make_uint2(rx, ry);
}

// ---------------- pad slots (dup of first record) + tail fill + chunk->node map ----------------
__global__ void k_pad(const int* __restrict__ offs, const int* __restrict__ counts,
                      uint2* __restrict__ ed, u16* __restrict__ mapc) {
  int i = blockIdx.x * 256 + threadIdx.x;
  if (i < M_NODE) {
    int start = offs[i], cnt = counts[i];
    if (cnt > 0) {
      int pad = (-cnt) & 3;
      if (pad) {
        uint2 f = ed[start];
        for (int k = 0; k < pad; k++) ed[start + cnt + k] = f;
      }
      int ch0 = start >> 2, ch1 = (start + cnt + 3) >> 2;
      for (int ch = ch0; ch < ch1; ch++) mapc[ch] = (u16)i;
    }
  }
  int total = offs[M_NODE];
  int pos = total + i;
  if (pos < ED_CAP) ed[pos] = make_uint2(0u, 0u);   // si=0, dxyz=0 (never computed)
}

// ---------------- z GEMM: z = vf @ We[0:256] + be (fp16 out) ----------------
__global__ __launch_bounds__(256)
void k_zgemm(const u16* __restrict__ A, const u16* __restrict__ WeT,
             const float* __restrict__ be, u16* __restrict__ zh)
{
  __shared__ __align__(16) u16 As[128*32];
  __shared__ __align__(16) u16 Bs[128*32];
  const int t  = threadIdx.x;
  const int n0 = blockIdx.x * 128;
  const int mb = blockIdx.y * 128;

  int r0 = mb + (t >> 2);      if (r0 >= M_NODE) r0 = 0;
  int r1 = mb + 64 + (t >> 2); if (r1 >= M_NODE) r1 = 0;
  const int ak = (((t & 3) ^ ((t >> 3) & 3)) << 3);
  const u16* asrc0 = A + (size_t)r0 * C_ + ak;
  const u16* asrc1 = A + (size_t)r1 * C_ + ak;
  const u16* bsrc0 = WeT + (size_t)(n0 + (t >> 2)) * C_ + ak;
  const u16* bsrc1 = WeT + (size_t)(n0 + 64 + (t >> 2)) * C_ + ak;

  const f32x4 zero = {0.f, 0.f, 0.f, 0.f};
  f32x4 acc[4][4];
  #pragma unroll
  for (int m = 0; m < 4; m++)
    #pragma unroll
    for (int n = 0; n < 4; n++) acc[m][n] = zero;

  const int lane = t & 63, wave = t >> 6;
  const int wr = wave >> 1, wc = wave & 1;
  const int lr = lane & 15, lch = lane >> 4;
  const int swz = (lr >> 1) & 3;

  for (int kk = 0; kk < 8; kk++) {
    const int k0 = kk * 32;
    async16(&As[t*8],        asrc0 + k0);
    async16(&As[(t+256)*8],  asrc1 + k0);
    async16(&Bs[t*8],        bsrc0 + k0);
    async16(&Bs[(t+256)*8],  bsrc1 + k0);
    __syncthreads();
    bf16x8 a[4], b[4];
    #pragma unroll
    for (int m = 0; m < 4; m++)
      a[m] = *(const bf16x8*)&As[(wr*64 + m*16 + lr)*32 + ((lch ^ swz) << 3)];
    #pragma unroll
    for (int n = 0; n < 4; n++)
      b[n] = *(const bf16x8*)&Bs[(wc*64 + n*16 + lr)*32 + ((lch ^ swz) << 3)];
    #pragma unroll
    for (int m = 0; m < 4; m++)
      #pragma unroll
      for (int n = 0; n < 4; n++)
        acc[m][n] = __builtin_amdgcn_mfma_f32_16x16x32_bf16(a[m], b[n], acc[m][n], 0, 0, 0);
    __syncthreads();
  }

  int gc[4]; float bias[4];
  #pragma unroll
  for (int n = 0; n < 4; n++) { int c = n0 + wc*64 + n*16 + lr; gc[n] = c; bias[n] = be[c]; }
  #pragma unroll
  for (int m = 0; m < 4; m++) {
    #pragma unroll
    for (int j = 0; j < 4; j++) {
      int r = mb + wr*64 + m*16 + lch*4 + j;
      if (r < M_NODE) {
        #pragma unroll
        for (int n = 0; n < 4; n++)
          zh[(size_t)r * C_ + gc[n]] = f2h(acc[m][n][j] + bias[n]);
      }
    }
  }
}

// ---------------- aggregation: flat chunk-stream, packed-f16 math, atomic flush ----------------
__global__ __launch_bounds__(256)
void k_agg(const u16* __restrict__ zh, const uint2* __restrict__ ed,
           const int* __restrict__ offs, const int* __restrict__ counts,
           const u16* __restrict__ mapc,
           const float* __restrict__ We, const float* __restrict__ ge,
           int* __restrict__ agg, float* __restrict__ esum, float* __restrict__ esumsq)
{
  const int lane = threadIdx.x & 63, wave = threadIdx.x >> 6;
  const int c0 = lane * 4;
  // packed f16 weights for xyz columns
  float4 w0f = *(const float4*)&We[256*C_ + c0];
  float4 w1f = *(const float4*)&We[257*C_ + c0];
  float4 w2f = *(const float4*)&We[258*C_ + c0];
  h2 w0[2] = { h2{(_Float16)w0f.x, (_Float16)w0f.y}, h2{(_Float16)w0f.z, (_Float16)w0f.w} };
  h2 w1[2] = { h2{(_Float16)w1f.x, (_Float16)w1f.y}, h2{(_Float16)w1f.z, (_Float16)w1f.w} };
  h2 w2[2] = { h2{(_Float16)w2f.x, (_Float16)w2f.y}, h2{(_Float16)w2f.z, (_Float16)w2f.w} };
  const u16* zp = zh + c0;

  float ps[4] = {0.f,0.f,0.f,0.f};
  float pq[4] = {0.f,0.f,0.f,0.f};

  const int T  = offs[M_NODE];          // padded slot total (multiple of 4)
  const int NC = T >> 2;                // chunk count
  const int NW = gridDim.x * 4;
  const int wid = blockIdx.x * 4 + wave;
  const int q = NC / NW, rw = NC % NW;
  int c        = wid * q + (wid < rw ? wid : rw);
  const int cEnd = c + q + (wid < rw ? 1 : 0);

  const h2 MXI = h2{(_Float16)-1.f, (_Float16)-1.f};
  const h2 MNI = h2{(_Float16)65504.f, (_Float16)65504.f};

  if (c < cEnd) {
    int cur = mapc[c];
    int vE  = offs[cur] + counts[cur];
    h2 mx[2] = {MXI, MXI};
    h2 mn[2] = {MNI, MNI};

    auto flush = [&](int node) {
      float4 gsv = *(const float4*)&ge[c0];
      int* ap = agg + (size_t)node * C_ + c0;
      float v0 = (float)mx[0].x, v1 = (float)mx[0].y, v2 = (float)mx[1].x, v3 = (float)mx[1].y;
      float u0 = (float)mn[0].x, u1 = (float)mn[0].y, u2 = (float)mn[1].x, u3 = (float)mn[1].y;
      if (gsv.x >= 0.f) atomicMax(ap+0, __float_as_int(v0)); else atomicMin(ap+0, __float_as_int(u0));
      if (gsv.y >= 0.f) atomicMax(ap+1, __float_as_int(v1)); else atomicMin(ap+1, __float_as_int(u1));
      if (gsv.z >= 0.f) atomicMax(ap+2, __float_as_int(v2)); else atomicMin(ap+2, __float_as_int(u2));
      if (gsv.w >= 0.f) atomicMax(ap+3, __float_as_int(v3)); else atomicMin(ap+3, __float_as_int(u3));
    };

    // prologue: records for c and c+1, z for c
    uint2 r0[4], r1[4], z0[4];
    #pragma unroll
    for (int k = 0; k < 4; k++) r0[k] = ed[c*4 + k];
    #pragma unroll
    for (int k = 0; k < 4; k++)
      z0[k] = *(const uint2*)(zp + ((size_t)(r0[k].y >> 16) << 8));
    #pragma unroll
    for (int k = 0; k < 4; k++) r1[k] = ed[c*4 + 4 + k];

    for (; c < cEnd; c++) {
      int nn = (int)mapc[c];                      // wave-uniform
      if (nn != cur) {
        flush(cur);
        mx[0] = MXI; mx[1] = MXI; mn[0] = MNI; mn[1] = MNI;
        cur = nn;
        vE = offs[cur] + counts[cur];
      }
      // issue z for chunk c+1 and records for chunk c+2 (stream, in-bounds via tail slack)
      uint2 z1[4], r2[4];
      #pragma unroll
      for (int k = 0; k < 4; k++)
        z1[k] = *(const uint2*)(zp + ((size_t)(r1[k].y >> 16) << 8));
      #pragma unroll
      for (int k = 0; k < 4; k++) r2[k] = ed[(c+2)*4 + k];

      const int sbase = c * 4;
      #pragma unroll
      for (int k = 0; k < 4; k++) {
        u32 rx = r0[k].x, ry = r0[k].y;
        h2 dxx = u2h2((rx & 0xffffu) | (rx << 16));
        h2 dyy = u2h2((rx >> 16) | (rx & 0xffff0000u));
        h2 dzz = u2h2((ry & 0xffffu) | (ry << 16));
        h2 za = u2h2(z0[k].x), zb = u2h2(z0[k].y);
        h2 y0 = dxx*w0[0] + dyy*w1[0] + dzz*w2[0] + za;
        h2 y1 = dxx*w0[1] + dyy*w1[1] + dzz*w2[1] + zb;
        const h2 zero2 = h2{(_Float16)0.f, (_Float16)0.f};
        y0 = __builtin_elementwise_max(y0, zero2);
        y1 = __builtin_elementwise_max(y1, zero2);
        mx[0] = __builtin_elementwise_max(mx[0], y0);
        mx[1] = __builtin_elementwise_max(mx[1], y1);
        mn[0] = __builtin_elementwise_min(mn[0], y0);
        mn[1] = __builtin_elementwise_min(mn[1], y1);
        if (sbase + k < vE) {                      // wave-uniform guard (excl. pad slots)
          float f0 = (float)y0.x, f1 = (float)y0.y, f2 = (float)y1.x, f3 = (float)y1.y;
          ps[0] += f0; pq[0] = fmaf(f0, f0, pq[0]);
          ps[1] += f1; pq[1] = fmaf(f1, f1, pq[1]);
          ps[2] += f2; pq[2] = fmaf(f2, f2, pq[2]);
          ps[3] += f3; pq[3] = fmaf(f3, f3, pq[3]);
        }
      }
      #pragma unroll
      for (int k = 0; k < 4; k++) { r0[k] = r1[k]; r1[k] = r2[k]; z0[k] = z1[k]; }
    }
    flush(cur);
  }

  // block-level stats reduction -> one atomicAdd per col
  __shared__ float red[4][256];
  #pragma unroll
  for (int j = 0; j < 4; j++) red[wave][c0 + j] = ps[j];
  __syncthreads();
  if (threadIdx.x < 256) {
    float s = red[0][threadIdx.x] + red[1][threadIdx.x] + red[2][threadIdx.x] + red[3][threadIdx.x];
    atomicAdd(&esum[threadIdx.x], s);
  }
  __syncthreads();
  #pragma unroll
  for (int j = 0; j < 4; j++) red[wave][c0 + j] = pq[j];
  __syncthreads();
  if (threadIdx.x < 256) {
    float s = red[0][threadIdx.x] + red[1][threadIdx.x] + red[2][threadIdx.x] + red[3][threadIdx.x];
    atomicAdd(&esumsq[threadIdx.x], s);
  }
}

// ---------------- BN stats -> scale/shift ----------------
__global__ void k_stats(const float* __restrict__ sum, const float* __restrict__ sumsq,
                        const float* __restrict__ g, const float* __restrict__ beta,
                        float cnt, float* __restrict__ scale, float* __restrict__ shift) {
  int c = threadIdx.x;
  float m = sum[c] / cnt;
  float v = sumsq[c] / cnt - m*m;
  v = fmaxf(v, 0.f);
  float s = g[c] * rsqrtf(v + EPS_);
  scale[c] = s;
  shift[c] = beta[c] - m*s;
}

// ---------------- agg -> normalized bf16 (empty segments -> 0) ----------------
__global__ void k_aggnorm(const float* __restrict__ agg, const int* __restrict__ counts,
                          const float* __restrict__ scale, const float* __restrict__ shift,
                          u32* __restrict__ out) {
  int i = blockIdx.x * 256 + threadIdx.x;       // pair index
  if (i >= M_NODE*C_/2) return;
  int n = (i*2) >> 8;
  int cbase = (i*2) & (C_-1);
  int cnt = counts[n];
  u32 r = 0;
  #pragma unroll
  for (int k = 0; k < 2; k++) {
    float val = (cnt > 0) ? fmaf(agg[(size_t)i*2 + k], scale[cbase + k], shift[cbase + k]) : 0.f;
    r |= ((u32)f2bf(val)) << (k*16);
  }
  out[i] = r;
}

// ---------------- u GEMM: y=relu(agg@Wu+b); stats; store y (bf16) ----------------
__global__ __launch_bounds__(256)
void k_ugemm(const u16* __restrict__ A, const u16* __restrict__ WuT,
             const float* __restrict__ bu,
             u16* __restrict__ yu, float* __restrict__ usum, float* __restrict__ usumsq)
{
  __shared__ __align__(16) u16 As[128*32];
  __shared__ __align__(16) u16 Bs[128*32];
  const int t  = threadIdx.x;
  const int n0 = blockIdx.x * 128;
  const int mb = blockIdx.y * 128;

  int r0 = mb + (t >> 2);      if (r0 >= M_NODE) r0 = 0;
  int r1 = mb + 64 + (t >> 2); if (r1 >= M_NODE) r1 = 0;
  const int ak = (((t & 3) ^ ((t >> 3) & 3)) << 3);
  const u16* asrc0 = A + (size_t)r0 * C_ + ak;
  const u16* asrc1 = A + (size_t)r1 * C_ + ak;
  const u16* bsrc0 = WuT + (size_t)(n0 + (t >> 2)) * C_ + ak;
  const u16* bsrc1 = WuT + (size_t)(n0 + 64 + (t >> 2)) * C_ + ak;

  const f32x4 zero = {0.f, 0.f, 0.f, 0.f};
  f32x4 acc[4][4];
  #pragma unroll
  for (int m = 0; m < 4; m++)
    #pragma unroll
    for (int n = 0; n < 4; n++) acc[m][n] = zero;

  const int lane = t & 63, wave = t >> 6;
  const int wr = wave >> 1, wc = wave & 1;
  const int lr = lane & 15, lch = lane >> 4;
  const int swz = (lr >> 1) & 3;

  for (int kk = 0; kk < 8; kk++) {
    const int k0 = kk * 32;
    async16(&As[t*8],        asrc0 + k0);
    async16(&As[(t+256)*8],  asrc1 + k0);
    async16(&Bs[t*8],        bsrc0 + k0);
    async16(&Bs[(t+256)*8],  bsrc1 + k0);
    __syncthreads();
    bf16x8 a[4], b[4];
    #pragma unroll
    for (int m = 0; m < 4; m++)
      a[m] = *(const bf16x8*)&As[(wr*64 + m*16 + lr)*32 + ((lch ^ swz) << 3)];
    #pragma unroll
    for (int n = 0; n < 4; n++)
      b[n] = *(const bf16x8*)&Bs[(wc*64 + n*16 + lr)*32 + ((lch ^ swz) << 3)];
    #pragma unroll
    for (int m = 0; m < 4; m++)
      #pragma unroll
      for (int n = 0; n < 4; n++)
        acc[m][n] = __builtin_amdgcn_mfma_f32_16x16x32_bf16(a[m], b[n], acc[m][n], 0, 0, 0);
    __syncthreads();
  }

  int gc[4]; float bias[4];
  #pragma unroll
  for (int n = 0; n < 4; n++) { int c = n0 + wc*64 + n*16 + lr; gc[n] = c; bias[n] = bu[c]; }
  float psum[4] = {0.f,0.f,0.f,0.f};
  float psq [4] = {0.f,0.f,0.f,0.f};
  #pragma unroll
  for (int m = 0; m < 4; m++) {
    #pragma unroll
    for (int j = 0; j < 4; j++) {
      int r = mb + wr*64 + m*16 + lch*4 + j;
      bool valid = r < M_NODE;
      #pragma unroll
      for (int n = 0; n < 4; n++) {
        float y = fmaxf(acc[m][n][j] + bias[n], 0.f);
        if (valid) {
          psum[n] += y;
          psq[n]  += y*y;
          yu[(size_t)r * C_ + gc[n]] = f2bf(y);
        }
      }
    }
  }
  #pragma unroll
  for (int n = 0; n < 4; n++) {
    float s1 = psum[n], s2 = psq[n];
    s1 += __shfl_xor(s1, 16, 64);  s2 += __shfl_xor(s2, 16, 64);
    s1 += __shfl_xor(s1, 32, 64);  s2 += __shfl_xor(s2, 32, 64);
    if (lch == 0) { atomicAdd(&usum[gc[n]], s1); atomicAdd(&usumsq[gc[n]], s2); }
  }
}

// ---------------- final: BN affine + residual + transpose to [B][C][N] ----------------
__global__ void k_final(const u16* __restrict__ yu, const float* __restrict__ feat,
                        const float* __restrict__ scale, const float* __restrict__ shift,
                        float* __restrict__ out) {
  __shared__ u16 tile[32][33];
  int tx = threadIdx.x & 31, ty = threadIdx.x >> 5;
  int b = blockIdx.z, c0 = blockIdx.y * 32, n0 = blockIdx.x * 32;
  #pragma unroll
  for (int i = 0; i < 4; i++) {
    int n = n0 + ty + i*8;
    tile[ty + i*8][tx] = (n < N_) ? yu[((size_t)(b*N_ + n))*C_ + c0 + tx] : (u16)0;
  }
  __syncthreads();
  int n = n0 + tx;
  if (n < N_) {
    #pragma unroll
    for (int i = 0; i < 4; i++) {
      int c = c0 + ty + i*8;
      float v = bf2f(tile[tx][ty + i*8]) * scale[c] + shift[c];
      out[((size_t)(b*C_ + c))*N_ + n] = v + feat[((size_t)(b*C_ + c))*N_ + n];
    }
  }
}

extern "C" void kernel_launch(void* const* d_in, const int* in_sizes, int n_in,
                              void* d_out, int out_size, void* d_ws, size_t ws_size,
                              hipStream_t stream) {
  const float* xyz  = (const float*)d_in[0];
  const float* feat = (const float*)d_in[1];
  const int*   edges= (const int*)  d_in[2];
  const float* We   = (const float*)d_in[3];
  const float* be   = (const float*)d_in[4];
  const float* ge   = (const float*)d_in[5];
  const float* bte  = (const float*)d_in[6];
  const float* Wu   = (const float*)d_in[7];
  const float* bu   = (const float*)d_in[8];
  const float* gu   = (const float*)d_in[9];
  const float* btu  = (const float*)d_in[10];
  float* out = (float*)d_out;

  char* w = (char*)d_ws;
  size_t off = 0;
  auto carve = [&](size_t bytes) -> void* {
    void* p = w + off;
    off = (off + bytes + 511) & ~(size_t)511;
    return p;
  };
  u16*  vf      = (u16*) carve((size_t)M_NODE*C_*2);       // 10.24 MB
  u16*  WeT     = (u16*) carve((size_t)C_*C_*2);
  u16*  WuT     = (u16*) carve((size_t)C_*C_*2);
  u16*  zh      = (u16*) carve((size_t)M_NODE*C_*2);       // 10.24 MB (fp16)
  uint2* ed     = (uint2*)carve((size_t)ED_CAP*8);         // 2.9 MB
  int*  counts  = (int*) carve((size_t)M_NODE*4);
  int*  offs    = (int*) carve((size_t)(M_NODE+1)*4);
  int*  cursor  = (int*) carve((size_t)M_NODE*4);
  u16*  mapc    = (u16*) carve((size_t)NC_CAP*2);          // chunk -> node
  int*  agg     = (int*) carve((size_t)M_NODE*C_*4);       // 20.48 MB (f32 bits)
  u32*  aggnorm = (u32*) carve((size_t)M_NODE*C_*2);       // 10.24 MB
  u16*  yu      = (u16*) carve((size_t)M_NODE*C_*2);       // 10.24 MB (bf16)
  float* stats  = (float*)carve(2048*4);
  float* esum = stats,        *esumsq = stats + 256;
  float* usum = stats + 512,  *usumsq = stats + 768;
  float* scale_e = stats + 1024, *shift_e = stats + 1280;
  float* scale_u = stats + 1536, *shift_u = stats + 1792;

  k_init<<<dim3(M_NODE), 256, 0, stream>>>(counts, stats, ge, agg);
  k_transpose_feat<<<dim3((N_+31)/32, C_/32, B_), 256, 0, stream>>>(feat, vf);
  k_transpose_w<<<dim3(C_/32, C_/32, 2), 256, 0, stream>>>(We, Wu, WeT, WuT);
  k_hist<<<dim3((M_EDGE + 255)/256), 256, 0, stream>>>(edges, counts);
  k_scan<<<1, 1024, 0, stream>>>(counts, offs, cursor);
  k_scatter<<<dim3((M_EDGE + 255)/256), 256, 0, stream>>>(edges, xyz, cursor, ed);
  k_pad<<<dim3((M_NODE + 255)/256), 256, 0, stream>>>(offs, counts, ed, mapc);
  k_zgemm<<<dim3(2, (M_NODE + 127)/128), 256, 0, stream>>>(vf, WeT, be, zh);
  k_agg<<<dim3(2048), 256, 0, stream>>>(zh, ed, offs, counts, mapc, We, ge, agg, esum, esumsq);
  k_stats<<<1, 256, 0, stream>>>(esum, esumsq, ge, bte, (float)M_EDGE, scale_e, shift_e);
  k_aggnorm<<<dim3(M_NODE*C_/512), 256, 0, stream>>>((const float*)agg, counts, scale_e, shift_e, aggnorm);
  k_ugemm<<<dim3(2, (M_NODE + 127)/128), 256, 0, stream>>>(
      (const u16*)aggnorm, WuT, bu, yu, usum, usumsq);
  k_stats<<<1, 256, 0, stream>>>(usum, usumsq, gu, btu, (float)M_NODE, scale_u, shift_u);
  k_final<<<dim3((N_+31)/32, C_/32, B_), 256, 0, stream>>>(yu, feat, scale_u, shift_u, out);
}

// Round 6
// 186.603 us; speedup vs baseline: 1.3377x; 1.3377x over previous
//
#include <hip/hip_runtime.h>

#define B_ 2
#define N_ 10000
#define E_ 150000
#define C_ 256
#define M_EDGE (B_*E_)   // 300000
#define M_NODE (B_*N_)   // 20000
#define ED_CAP (M_EDGE + 3*M_NODE + 64)   // padded CSR capacity + tail slack
#define NW_ 8192                           // k_agg waves (2048 blocks x 4)
#define EPS_ 1e-5f

typedef unsigned short u16;
typedef unsigned int   u32;
typedef __attribute__((ext_vector_type(8))) __bf16 bf16x8;
typedef __attribute__((ext_vector_type(4))) float  f32x4;
typedef _Float16 h2 __attribute__((ext_vector_type(2)));

__device__ __forceinline__ u16 f2bf(float x) {
  union { float f; u32 u; } v; v.f = x;
  u32 r = v.u + 0x7FFFu + ((v.u >> 16) & 1u);   // RNE
  return (u16)(r >> 16);
}
__device__ __forceinline__ float bf2f(u16 x) {
  union { u32 u; float f; } v; v.u = ((u32)x) << 16; return v.f;
}
__device__ __forceinline__ u16 f2h(float x) {
  _Float16 h = (_Float16)x;
  union { _Float16 h; u16 u; } v; v.h = h; return v.u;
}
__device__ __forceinline__ h2 u2h2(u32 x) {
  union { u32 u; h2 h; } v; v.u = x; return v.h;
}
__device__ __forceinline__ u32 h22u(h2 x) {
  union { h2 h; u32 u; } v; v.h = x; return v.u;
}

__device__ __forceinline__ void async16(void* lds, const void* g) {
  __builtin_amdgcn_global_load_lds(
      (const __attribute__((address_space(1))) void*)g,
      (__attribute__((address_space(3))) void*)lds, 16, 0, 0);
}

// ---------------- init: zero counts + stats ----------------
__global__ void k_init(int* __restrict__ counts, float* __restrict__ stats) {
  int i = blockIdx.x * 256 + threadIdx.x;
  if (i < M_NODE) counts[i] = 0;
  if (i < 1024) stats[i] = 0.f;
}

// ---------------- features [B][C][N] f32 -> vf [B][N][C] bf16 ----------------
__global__ void k_transpose_feat(const float* __restrict__ f, u16* __restrict__ vf) {
  __shared__ float tile[32][33];
  int tx = threadIdx.x & 31, ty = threadIdx.x >> 5;
  int b = blockIdx.z, c0 = blockIdx.y * 32, n0 = blockIdx.x * 32;
  #pragma unroll
  for (int i = 0; i < 4; i++) {
    int c = c0 + ty + i*8, n = n0 + tx;
    tile[ty + i*8][tx] = (n < N_) ? f[((size_t)(b*C_ + c))*N_ + n] : 0.f;
  }
  __syncthreads();
  #pragma unroll
  for (int i = 0; i < 4; i++) {
    int n = n0 + ty + i*8, c = c0 + tx;
    if (n < N_) vf[((size_t)(b*N_ + n))*C_ + c] = f2bf(tile[tx][ty + i*8]);
  }
}

// ---------------- W_e[0:256][:], W_u -> transposed bf16 [Cout][K] ----------------
__global__ void k_transpose_w(const float* __restrict__ We, const float* __restrict__ Wu,
                              u16* __restrict__ WeT, u16* __restrict__ WuT) {
  __shared__ float tile[32][33];
  const float* src = blockIdx.z ? Wu : We;
  u16* dst = blockIdx.z ? WuT : WeT;
  int tx = threadIdx.x & 31, ty = threadIdx.x >> 5;
  int r0 = blockIdx.y * 32, c0 = blockIdx.x * 32;
  #pragma unroll
  for (int i = 0; i < 4; i++)
    tile[ty + i*8][tx] = src[(size_t)(r0 + ty + i*8)*C_ + c0 + tx];
  __syncthreads();
  #pragma unroll
  for (int i = 0; i < 4; i++)
    dst[(size_t)(c0 + ty + i*8)*C_ + r0 + tx] = f2bf(tile[tx][ty + i*8]);
}

// ---------------- histogram of dst ----------------
__global__ void k_hist(const int* __restrict__ edges, int* __restrict__ counts) {
  int i = blockIdx.x * 256 + threadIdx.x;
  if (i >= M_EDGE) return;
  int b = (i >= E_) ? 1 : 0;
  int e = i - b * E_;
  int d = edges[(size_t)(b*2 + 1)*E_ + e];
  atomicAdd(&counts[b*N_ + d], 1);
}

// ---------------- exclusive scan of PADDED counts (single block) ----------------
__global__ __launch_bounds__(1024)
void k_scan(const int* __restrict__ counts, int* __restrict__ offs, int* __restrict__ cursor) {
  __shared__ int part[1024];
  int t = threadIdx.x;
  int base = t * 20;
  int vals[20];
  if (t < 1000) {
    #pragma unroll
    for (int j = 0; j < 5; j++)
      *(int4*)&vals[j*4] = *(const int4*)&counts[base + j*4];
  } else {
    #pragma unroll
    for (int i = 0; i < 20; i++) vals[i] = 0;
  }
  int local[20];
  int s = 0;
  #pragma unroll
  for (int i = 0; i < 20; i++) {
    int pv = (vals[i] + 3) & ~3;          // pad each node to multiple of 4
    local[i] = s; s += pv;
  }
  part[t] = s;
  __syncthreads();
  for (int d = 1; d < 1024; d <<= 1) {
    int v = (t >= d) ? part[t - d] : 0;
    __syncthreads();
    part[t] += v;
    __syncthreads();
  }
  int excl = (t == 0) ? 0 : part[t - 1];
  if (t < 1000) {
    #pragma unroll
    for (int j = 0; j < 5; j++) {
      int4 o;
      o.x = excl + local[j*4 + 0];
      o.y = excl + local[j*4 + 1];
      o.z = excl + local[j*4 + 2];
      o.w = excl + local[j*4 + 3];
      *(int4*)&offs[base + j*4]   = o;
      *(int4*)&cursor[base + j*4] = o;
    }
  }
  if (t == 1023) offs[M_NODE] = part[1023];   // total padded size
}

// ---------------- scatter edges into padded CSR slots (packed 8B records) ----------------
// rec.x = f16(dx) | f16(dy)<<16 ; rec.y = f16(dz) | src_node<<16
__global__ void k_scatter(const int* __restrict__ edges, const float* __restrict__ xyz,
                          int* __restrict__ cursor, uint2* __restrict__ ed) {
  int i = blockIdx.x * 256 + threadIdx.x;
  if (i >= M_EDGE) return;
  int b = (i >= E_) ? 1 : 0;
  int e = i - b * E_;
  int s = edges[(size_t)(b*2 + 0)*E_ + e];
  int d = edges[(size_t)(b*2 + 1)*E_ + e];
  const float* ps = xyz + ((size_t)(b*N_ + s))*3;
  const float* pd = xyz + ((size_t)(b*N_ + d))*3;
  int pos = atomicAdd(&cursor[b*N_ + d], 1);
  u32 rx = (u32)f2h(ps[0]-pd[0]) | ((u32)f2h(ps[1]-pd[1]) << 16);
  u32 ry = (u32)f2h(ps[2]-pd[2]) | ((u32)(b*N_ + s) << 16);
  ed[pos] = make_uint2(rx, ry);
}

// ------- pad dup fill + tail fill + nodeInfo + waveStart table -------
// nodeInfo[n] = (paddedEnd << 10) | cnt     (cnt < 1024 guaranteed for this data)
// waveStart[w] = lower_bound(offs, w*SPW)   (first node whose padded segment starts >= w*SPW)
__global__ void k_pad(const int* __restrict__ offs, const int* __restrict__ counts,
                      uint2* __restrict__ ed, u32* __restrict__ nodeInfo,
                      int* __restrict__ waveStart) {
  int i = blockIdx.x * 256 + threadIdx.x;
  const int T = offs[M_NODE];
  const int SPW = (T + NW_ - 1) / NW_;
  if (i < M_NODE) {
    int s = offs[i], e = offs[i+1];
    int cnt = counts[i];
    if (cnt > 0) {
      int pad = e - (s + cnt);
      if (pad) {
        uint2 f = ed[s];
        for (int k = 0; k < pad; k++) ed[s + cnt + k] = f;
      }
    }
    nodeInfo[i] = ((u32)e << 10) | (u32)cnt;
    int lo = (i == 0) ? 0 : offs[i-1] + 1;
    int wlo = (lo + SPW - 1) / SPW;
    int whi = offs[i] / SPW;
    for (int w = wlo; w <= whi && w <= NW_; w++) waveStart[w] = i;
  }
  if (i == M_NODE) {
    nodeInfo[M_NODE]   = ((u32)T << 10);
    nodeInfo[M_NODE+1] = ((u32)T << 10);
    int lo = offs[M_NODE-1] + 1;
    int wlo = (lo + SPW - 1) / SPW;
    if (wlo < 0) wlo = 0;
    for (int w = wlo; w <= NW_; w++) waveStart[w] = M_NODE;
  }
  int pos = T + i;
  if (pos < ED_CAP) ed[pos] = make_uint2(0u, 0u);   // tail: si=0, never processed
}

// ---------------- z GEMM: z = vf @ We[0:256] + be (fp16 out) ----------------
__global__ __launch_bounds__(256)
void k_zgemm(const u16* __restrict__ A, const u16* __restrict__ WeT,
             const float* __restrict__ be, u16* __restrict__ zh)
{
  __shared__ __align__(16) u16 As[128*32];
  __shared__ __align__(16) u16 Bs[128*32];
  const int t  = threadIdx.x;
  const int n0 = blockIdx.x * 128;
  const int mb = blockIdx.y * 128;

  int r0 = mb + (t >> 2);      if (r0 >= M_NODE) r0 = 0;
  int r1 = mb + 64 + (t >> 2); if (r1 >= M_NODE) r1 = 0;
  const int ak = (((t & 3) ^ ((t >> 3) & 3)) << 3);
  const u16* asrc0 = A + (size_t)r0 * C_ + ak;
  const u16* asrc1 = A + (size_t)r1 * C_ + ak;
  const u16* bsrc0 = WeT + (size_t)(n0 + (t >> 2)) * C_ + ak;
  const u16* bsrc1 = WeT + (size_t)(n0 + 64 + (t >> 2)) * C_ + ak;

  const f32x4 zero = {0.f, 0.f, 0.f, 0.f};
  f32x4 acc[4][4];
  #pragma unroll
  for (int m = 0; m < 4; m++)
    #pragma unroll
    for (int n = 0; n < 4; n++) acc[m][n] = zero;

  const int lane = t & 63, wave = t >> 6;
  const int wr = wave >> 1, wc = wave & 1;
  const int lr = lane & 15, lch = lane >> 4;
  const int swz = (lr >> 1) & 3;

  for (int kk = 0; kk < 8; kk++) {
    const int k0 = kk * 32;
    async16(&As[t*8],        asrc0 + k0);
    async16(&As[(t+256)*8],  asrc1 + k0);
    async16(&Bs[t*8],        bsrc0 + k0);
    async16(&Bs[(t+256)*8],  bsrc1 + k0);
    __syncthreads();
    bf16x8 a[4], b[4];
    #pragma unroll
    for (int m = 0; m < 4; m++)
      a[m] = *(const bf16x8*)&As[(wr*64 + m*16 + lr)*32 + ((lch ^ swz) << 3)];
    #pragma unroll
    for (int n = 0; n < 4; n++)
      b[n] = *(const bf16x8*)&Bs[(wc*64 + n*16 + lr)*32 + ((lch ^ swz) << 3)];
    #pragma unroll
    for (int m = 0; m < 4; m++)
      #pragma unroll
      for (int n = 0; n < 4; n++)
        acc[m][n] = __builtin_amdgcn_mfma_f32_16x16x32_bf16(a[m], b[n], acc[m][n], 0, 0, 0);
    __syncthreads();
  }

  int gc[4]; float bias[4];
  #pragma unroll
  for (int n = 0; n < 4; n++) { int c = n0 + wc*64 + n*16 + lr; gc[n] = c; bias[n] = be[c]; }
  #pragma unroll
  for (int m = 0; m < 4; m++) {
    #pragma unroll
    for (int j = 0; j < 4; j++) {
      int r = mb + wr*64 + m*16 + lch*4 + j;
      if (r < M_NODE) {
        #pragma unroll
        for (int n = 0; n < 4; n++)
          zh[(size_t)r * C_ + gc[n]] = f2h(acc[m][n][j] + bias[n]);
      }
    }
  }
}

// -------- aggregation: node-aligned flat stream, 3-phase pipeline, plain stores --------
__global__ __launch_bounds__(256)
void k_agg(const u16* __restrict__ zh, const uint2* __restrict__ ed,
           const int* __restrict__ offs, const u32* __restrict__ nodeInfo,
           const int* __restrict__ waveStart,
           const float* __restrict__ We, const float* __restrict__ ge,
           u32* __restrict__ aggh, float* __restrict__ esum, float* __restrict__ esumsq)
{
  const int lane = threadIdx.x & 63, wave = threadIdx.x >> 6;
  const int c0 = lane * 4;
  float4 w0f = *(const float4*)&We[256*C_ + c0];
  float4 w1f = *(const float4*)&We[257*C_ + c0];
  float4 w2f = *(const float4*)&We[258*C_ + c0];
  h2 w0[2] = { h2{(_Float16)w0f.x, (_Float16)w0f.y}, h2{(_Float16)w0f.z, (_Float16)w0f.w} };
  h2 w1[2] = { h2{(_Float16)w1f.x, (_Float16)w1f.y}, h2{(_Float16)w1f.z, (_Float16)w1f.w} };
  h2 w2[2] = { h2{(_Float16)w2f.x, (_Float16)w2f.y}, h2{(_Float16)w2f.z, (_Float16)w2f.w} };
  const float4 gs = *(const float4*)&ge[c0];
  const u16* zp = zh + c0;

  float ps[4] = {0.f,0.f,0.f,0.f};
  float pq[4] = {0.f,0.f,0.f,0.f};

  const int wid  = blockIdx.x * 4 + wave;
  int cur        = waveStart[wid];
  const int nEnd = waveStart[wid + 1];

  const h2 MXI = h2{(_Float16)-1.f, (_Float16)-1.f};
  const h2 MNI = h2{(_Float16)65504.f, (_Float16)65504.f};

  if (cur < nEnd) {
    const int slotBeg = offs[cur];
    const int slotEnd = offs[nEnd];
    if (slotEnd > slotBeg) {
      // skip leading empty nodes (zero padded length)
      u32 info = nodeInfo[cur];
      while ((int)(info >> 10) == slotBeg) { cur++; info = nodeInfo[cur]; }
      int curEnd   = (int)(info >> 10);
      int vE       = slotBeg + (int)(info & 1023u);
      u32 nextInfo = nodeInfo[cur + 1];

      h2 mx0 = MXI, mx1 = MXI, mn0 = MNI, mn1 = MNI;

      const uint2* edp = ed + slotBeg;
      const int nc = (slotEnd - slotBeg) >> 2;

      auto zld = [&](uint2 r) -> uint2 {
        return *(const uint2*)(zp + ((size_t)(r.y >> 16) << 8));
      };
      auto flush = [&](int node) {
        h2 s0, s1;
        s0.x = (gs.x >= 0.f) ? mx0.x : mn0.x;
        s0.y = (gs.y >= 0.f) ? mx0.y : mn0.y;
        s1.x = (gs.z >= 0.f) ? mx1.x : mn1.x;
        s1.y = (gs.w >= 0.f) ? mx1.y : mn1.y;
        *(uint2*)(aggh + (size_t)node * 128 + lane * 2) = make_uint2(h22u(s0), h22u(s1));
      };
      auto processChunk = [&](int ci, const uint2 (&R)[4], const uint2 (&Z)[4]) {
        const int slot = slotBeg + ci * 4;
        if (slot == curEnd) {                       // node boundary (chunk-aligned)
          flush(cur);
          mx0 = MXI; mx1 = MXI; mn0 = MNI; mn1 = MNI;
          cur++;
          u32 inf = nextInfo;
          while ((int)(inf >> 10) == curEnd) { cur++; inf = nodeInfo[cur]; }
          vE = curEnd + (int)(inf & 1023u);
          curEnd = (int)(inf >> 10);
          nextInfo = nodeInfo[cur + 1];
        }
        #pragma unroll
        for (int k = 0; k < 4; k++) {
          u32 rx = R[k].x, ry = R[k].y;
          h2 dxx = u2h2((rx & 0xffffu) | (rx << 16));
          h2 dyy = u2h2((rx >> 16) | (rx & 0xffff0000u));
          h2 dzz = u2h2((ry & 0xffffu) | (ry << 16));
          h2 za = u2h2(Z[k].x), zb = u2h2(Z[k].y);
          h2 y0 = dxx*w0[0] + dyy*w1[0] + dzz*w2[0] + za;
          h2 y1 = dxx*w0[1] + dyy*w1[1] + dzz*w2[1] + zb;
          const h2 zero2 = h2{(_Float16)0.f, (_Float16)0.f};
          y0 = __builtin_elementwise_max(y0, zero2);
          y1 = __builtin_elementwise_max(y1, zero2);
          mx0 = __builtin_elementwise_max(mx0, y0);
          mx1 = __builtin_elementwise_max(mx1, y1);
          mn0 = __builtin_elementwise_min(mn0, y0);
          mn1 = __builtin_elementwise_min(mn1, y1);
          if (slot + k < vE) {                      // wave-uniform (exclude pad slots)
            float f0 = (float)y0.x, f1 = (float)y0.y, f2 = (float)y1.x, f3 = (float)y1.y;
            ps[0] += f0; pq[0] = fmaf(f0, f0, pq[0]);
            ps[1] += f1; pq[1] = fmaf(f1, f1, pq[1]);
            ps[2] += f2; pq[2] = fmaf(f2, f2, pq[2]);
            ps[3] += f3; pq[3] = fmaf(f3, f3, pq[3]);
          }
        }
      };

      // ---- 3-phase software pipeline, statically named buffers, no rotation copies ----
      uint2 Ra[4], Rb[4], Rc[4], Za[4], Zb[4], Zc[4];
      #pragma unroll
      for (int k = 0; k < 4; k++) Ra[k] = edp[k];
      #pragma unroll
      for (int k = 0; k < 4; k++) Rb[k] = edp[4 + k];
      #pragma unroll
      for (int k = 0; k < 4; k++) Za[k] = zld(Ra[k]);

      for (int i = 0; i < nc; i += 3) {
        {
          #pragma unroll
          for (int k = 0; k < 4; k++) Rc[k] = edp[(i+2)*4 + k];
          #pragma unroll
          for (int k = 0; k < 4; k++) Zb[k] = zld(Rb[k]);
          processChunk(i, Ra, Za);
        }
        if (i + 1 < nc) {
          #pragma unroll
          for (int k = 0; k < 4; k++) Ra[k] = edp[(i+3)*4 + k];
          #pragma unroll
          for (int k = 0; k < 4; k++) Zc[k] = zld(Rc[k]);
          processChunk(i + 1, Rb, Zb);
        }
        if (i + 2 < nc) {
          #pragma unroll
          for (int k = 0; k < 4; k++) Rb[k] = edp[(i+4)*4 + k];
          #pragma unroll
          for (int k = 0; k < 4; k++) Za[k] = zld(Ra[k]);
          processChunk(i + 2, Rc, Zc);
        }
      }
      flush(cur);
    }
  }

  // block-level stats reduction -> one atomicAdd per col
  __shared__ float red[4][256];
  #pragma unroll
  for (int j = 0; j < 4; j++) red[wave][c0 + j] = ps[j];
  __syncthreads();
  if (threadIdx.x < 256) {
    float s = red[0][threadIdx.x] + red[1][threadIdx.x] + red[2][threadIdx.x] + red[3][threadIdx.x];
    atomicAdd(&esum[threadIdx.x], s);
  }
  __syncthreads();
  #pragma unroll
  for (int j = 0; j < 4; j++) red[wave][c0 + j] = pq[j];
  __syncthreads();
  if (threadIdx.x < 256) {
    float s = red[0][threadIdx.x] + red[1][threadIdx.x] + red[2][threadIdx.x] + red[3][threadIdx.x];
    atomicAdd(&esumsq[threadIdx.x], s);
  }
}

// ---------------- BN stats -> scale/shift ----------------
__global__ void k_stats(const float* __restrict__ sum, const float* __restrict__ sumsq,
                        const float* __restrict__ g, const float* __restrict__ beta,
                        float cnt, float* __restrict__ scale, float* __restrict__ shift) {
  int c = threadIdx.x;
  float m = sum[c] / cnt;
  float v = sumsq[c] / cnt - m*m;
  v = fmaxf(v, 0.f);
  float s = g[c] * rsqrtf(v + EPS_);
  scale[c] = s;
  shift[c] = beta[c] - m*s;
}

// ---------------- agg (packed f16) -> normalized bf16 (empty segments -> 0) ----------------
__global__ void k_aggnorm(const u32* __restrict__ aggh, const int* __restrict__ counts,
                          const float* __restrict__ scale, const float* __restrict__ shift,
                          u32* __restrict__ out) {
  int i = blockIdx.x * 256 + threadIdx.x;       // u32 pair index
  if (i >= M_NODE*C_/2) return;
  int n = i >> 7;
  int p = (i & 127) * 2;                        // channel base
  int cnt = counts[n];
  h2 hv = u2h2(aggh[i]);
  float v0 = (cnt > 0) ? fmaf((float)hv.x, scale[p],   shift[p])   : 0.f;
  float v1 = (cnt > 0) ? fmaf((float)hv.y, scale[p+1], shift[p+1]) : 0.f;
  out[i] = ((u32)f2bf(v0)) | (((u32)f2bf(v1)) << 16);
}

// ---------------- u GEMM: y=relu(agg@Wu+b); stats; store y (bf16) ----------------
__global__ __launch_bounds__(256)
void k_ugemm(const u16* __restrict__ A, const u16* __restrict__ WuT,
             const float* __restrict__ bu,
             u16* __restrict__ yu, float* __restrict__ usum, float* __restrict__ usumsq)
{
  __shared__ __align__(16) u16 As[128*32];
  __shared__ __align__(16) u16 Bs[128*32];
  const int t  = threadIdx.x;
  const int n0 = blockIdx.x * 128;
  const int mb = blockIdx.y * 128;

  int r0 = mb + (t >> 2);      if (r0 >= M_NODE) r0 = 0;
  int r1 = mb + 64 + (t >> 2); if (r1 >= M_NODE) r1 = 0;
  const int ak = (((t & 3) ^ ((t >> 3) & 3)) << 3);
  const u16* asrc0 = A + (size_t)r0 * C_ + ak;
  const u16* asrc1 = A + (size_t)r1 * C_ + ak;
  const u16* bsrc0 = WuT + (size_t)(n0 + (t >> 2)) * C_ + ak;
  const u16* bsrc1 = WuT + (size_t)(n0 + 64 + (t >> 2)) * C_ + ak;

  const f32x4 zero = {0.f, 0.f, 0.f, 0.f};
  f32x4 acc[4][4];
  #pragma unroll
  for (int m = 0; m < 4; m++)
    #pragma unroll
    for (int n = 0; n < 4; n++) acc[m][n] = zero;

  const int lane = t & 63, wave = t >> 6;
  const int wr = wave >> 1, wc = wave & 1;
  const int lr = lane & 15, lch = lane >> 4;
  const int swz = (lr >> 1) & 3;

  for (int kk = 0; kk < 8; kk++) {
    const int k0 = kk * 32;
    async16(&As[t*8],        asrc0 + k0);
    async16(&As[(t+256)*8],  asrc1 + k0);
    async16(&Bs[t*8],        bsrc0 + k0);
    async16(&Bs[(t+256)*8],  bsrc1 + k0);
    __syncthreads();
    bf16x8 a[4], b[4];
    #pragma unroll
    for (int m = 0; m < 4; m++)
      a[m] = *(const bf16x8*)&As[(wr*64 + m*16 + lr)*32 + ((lch ^ swz) << 3)];
    #pragma unroll
    for (int n = 0; n < 4; n++)
      b[n] = *(const bf16x8*)&Bs[(wc*64 + n*16 + lr)*32 + ((lch ^ swz) << 3)];
    #pragma unroll
    for (int m = 0; m < 4; m++)
      #pragma unroll
      for (int n = 0; n < 4; n++)
        acc[m][n] = __builtin_amdgcn_mfma_f32_16x16x32_bf16(a[m], b[n], acc[m][n], 0, 0, 0);
    __syncthreads();
  }

  int gc[4]; float bias[4];
  #pragma unroll
  for (int n = 0; n < 4; n++) { int c = n0 + wc*64 + n*16 + lr; gc[n] = c; bias[n] = bu[c]; }
  float psum[4] = {0.f,0.f,0.f,0.f};
  float psq [4] = {0.f,0.f,0.f,0.f};
  #pragma unroll
  for (int m = 0; m < 4; m++) {
    #pragma unroll
    for (int j = 0; j < 4; j++) {
      int r = mb + wr*64 + m*16 + lch*4 + j;
      bool valid = r < M_NODE;
      #pragma unroll
      for (int n = 0; n < 4; n++) {
        float y = fmaxf(acc[m][n][j] + bias[n], 0.f);
        if (valid) {
          psum[n] += y;
          psq[n]  += y*y;
          yu[(size_t)r * C_ + gc[n]] = f2bf(y);
        }
      }
    }
  }
  #pragma unroll
  for (int n = 0; n < 4; n++) {
    float s1 = psum[n], s2 = psq[n];
    s1 += __shfl_xor(s1, 16, 64);  s2 += __shfl_xor(s2, 16, 64);
    s1 += __shfl_xor(s1, 32, 64);  s2 += __shfl_xor(s2, 32, 64);
    if (lch == 0) { atomicAdd(&usum[gc[n]], s1); atomicAdd(&usumsq[gc[n]], s2); }
  }
}

// -------- final: BN affine + residual (bf16 vf) + transpose to [B][C][N] --------
__global__ void k_final(const u16* __restrict__ yu, const u16* __restrict__ vf,
                        const float* __restrict__ scale, const float* __restrict__ shift,
                        float* __restrict__ out) {
  __shared__ float tile[32][33];
  int tx = threadIdx.x & 31, ty = threadIdx.x >> 5;
  int b = blockIdx.z, c0 = blockIdx.y * 32, n0 = blockIdx.x * 32;
  #pragma unroll
  for (int i = 0; i < 4; i++) {
    int n = n0 + ty + i*8, c = c0 + tx;
    float v = 0.f;
    if (n < N_) {
      size_t idx = ((size_t)(b*N_ + n))*C_ + c;
      v = bf2f(yu[idx]) * scale[c] + shift[c] + bf2f(vf[idx]);
    }
    tile[ty + i*8][tx] = v;
  }
  __syncthreads();
  int n = n0 + tx;
  if (n < N_) {
    #pragma unroll
    for (int i = 0; i < 4; i++) {
      int c = c0 + ty + i*8;
      out[((size_t)(b*C_ + c))*N_ + n] = tile[tx][ty + i*8];
    }
  }
}

extern "C" void kernel_launch(void* const* d_in, const int* in_sizes, int n_in,
                              void* d_out, int out_size, void* d_ws, size_t ws_size,
                              hipStream_t stream) {
  const float* xyz  = (const float*)d_in[0];
  const float* feat = (const float*)d_in[1];
  const int*   edges= (const int*)  d_in[2];
  const float* We   = (const float*)d_in[3];
  const float* be   = (const float*)d_in[4];
  const float* ge   = (const float*)d_in[5];
  const float* bte  = (const float*)d_in[6];
  const float* Wu   = (const float*)d_in[7];
  const float* bu   = (const float*)d_in[8];
  const float* gu   = (const float*)d_in[9];
  const float* btu  = (const float*)d_in[10];
  float* out = (float*)d_out;

  char* w = (char*)d_ws;
  size_t off = 0;
  auto carve = [&](size_t bytes) -> void* {
    void* p = w + off;
    off = (off + bytes + 511) & ~(size_t)511;
    return p;
  };
  u16*  vf       = (u16*) carve((size_t)M_NODE*C_*2);       // 10.24 MB
  u16*  WeT      = (u16*) carve((size_t)C_*C_*2);
  u16*  WuT      = (u16*) carve((size_t)C_*C_*2);
  u16*  zh       = (u16*) carve((size_t)M_NODE*C_*2);       // 10.24 MB (fp16)
  uint2* ed      = (uint2*)carve((size_t)ED_CAP*8);         // 2.9 MB
  int*  counts   = (int*) carve((size_t)M_NODE*4);
  int*  offs     = (int*) carve((size_t)(M_NODE+1)*4);
  int*  cursor   = (int*) carve((size_t)M_NODE*4);
  u32*  nodeInfo = (u32*) carve((size_t)(M_NODE+2)*4);
  int*  waveStart= (int*) carve((size_t)(NW_+1)*4);
  u32*  aggh     = (u32*) carve((size_t)M_NODE*128*4);      // 10.24 MB (packed f16)
  u32*  aggnorm  = (u32*) carve((size_t)M_NODE*C_*2);       // 10.24 MB (bf16)
  u16*  yu       = (u16*) carve((size_t)M_NODE*C_*2);       // 10.24 MB (bf16)
  float* stats   = (float*)carve(2048*4);
  float* esum = stats,        *esumsq = stats + 256;
  float* usum = stats + 512,  *usumsq = stats + 768;
  float* scale_e = stats + 1024, *shift_e = stats + 1280;
  float* scale_u = stats + 1536, *shift_u = stats + 1792;

  k_init<<<dim3((M_NODE + 255)/256), 256, 0, stream>>>(counts, stats);
  k_transpose_feat<<<dim3((N_+31)/32, C_/32, B_), 256, 0, stream>>>(feat, vf);
  k_transpose_w<<<dim3(C_/32, C_/32, 2), 256, 0, stream>>>(We, Wu, WeT, WuT);
  k_hist<<<dim3((M_EDGE + 255)/256), 256, 0, stream>>>(edges, counts);
  k_scan<<<1, 1024, 0, stream>>>(counts, offs, cursor);
  k_scatter<<<dim3((M_EDGE + 255)/256), 256, 0, stream>>>(edges, xyz, cursor, ed);
  k_pad<<<dim3((M_NODE + 255)/256), 256, 0, stream>>>(offs, counts, ed, nodeInfo, waveStart);
  k_zgemm<<<dim3(2, (M_NODE + 127)/128), 256, 0, stream>>>(vf, WeT, be, zh);
  k_agg<<<dim3(NW_/4), 256, 0, stream>>>(zh, ed, offs, nodeInfo, waveStart,
                                         We, ge, aggh, esum, esumsq);
  k_stats<<<1, 256, 0, stream>>>(esum, esumsq, ge, bte, (float)M_EDGE, scale_e, shift_e);
  k_aggnorm<<<dim3(M_NODE*C_/512), 256, 0, stream>>>(aggh, counts, scale_e, shift_e, aggnorm);
  k_ugemm<<<dim3(2, (M_NODE + 127)/128), 256, 0, stream>>>(
      (const u16*)aggnorm, WuT, bu, yu, usum, usumsq);
  k_stats<<<1, 256, 0, stream>>>(usum, usumsq, gu, btu, (float)M_NODE, scale_u, shift_u);
  k_final<<<dim3((N_+31)/32, C_/32, B_), 256, 0, stream>>>(yu, vf, scale_u, shift_u, out);
}

// Round 7
// 184.720 us; speedup vs baseline: 1.3513x; 1.0102x over previous
//
#include <hip/hip_runtime.h>

#define B_ 2
#define N_ 10000
#define E_ 150000
#define C_ 256
#define M_EDGE (B_*E_)   // 300000
#define M_NODE (B_*N_)   // 20000
#define ED_CAP (M_EDGE + 3*M_NODE + 64)   // padded CSR capacity + tail slack
#define NW_ 8192                           // k_agg streams (2048 blocks x 4)
#define EPS_ 1e-5f

typedef unsigned short u16;
typedef unsigned int   u32;
typedef __attribute__((ext_vector_type(8))) __bf16 bf16x8;
typedef __attribute__((ext_vector_type(4))) float  f32x4;
typedef _Float16 h2 __attribute__((ext_vector_type(2)));

__device__ __forceinline__ u16 f2bf(float x) {
  union { float f; u32 u; } v; v.f = x;
  u32 r = v.u + 0x7FFFu + ((v.u >> 16) & 1u);   // RNE
  return (u16)(r >> 16);
}
__device__ __forceinline__ float bf2f(u16 x) {
  union { u32 u; float f; } v; v.u = ((u32)x) << 16; return v.f;
}
__device__ __forceinline__ u16 f2h(float x) {
  _Float16 h = (_Float16)x;
  union { _Float16 h; u16 u; } v; v.h = h; return v.u;
}
__device__ __forceinline__ h2 u2h2(u32 x) {
  union { u32 u; h2 h; } v; v.u = x; return v.h;
}
__device__ __forceinline__ u32 h22u(h2 x) {
  union { h2 h; u32 u; } v; v.h = x; return v.u;
}

__device__ __forceinline__ void async16(void* lds, const void* g) {
  __builtin_amdgcn_global_load_lds(
      (const __attribute__((address_space(1))) void*)g,
      (__attribute__((address_space(3))) void*)lds, 16, 0, 0);
}

// ---------------- init: zero counts + stats ----------------
__global__ void k_init(int* __restrict__ counts, float* __restrict__ stats) {
  int i = blockIdx.x * 256 + threadIdx.x;
  if (i < M_NODE) counts[i] = 0;
  if (i < 1024) stats[i] = 0.f;
}

// ---------------- features [B][C][N] f32 -> vf [B][N][C] bf16 ----------------
__global__ void k_transpose_feat(const float* __restrict__ f, u16* __restrict__ vf) {
  __shared__ float tile[32][33];
  int tx = threadIdx.x & 31, ty = threadIdx.x >> 5;
  int b = blockIdx.z, c0 = blockIdx.y * 32, n0 = blockIdx.x * 32;
  #pragma unroll
  for (int i = 0; i < 4; i++) {
    int c = c0 + ty + i*8, n = n0 + tx;
    tile[ty + i*8][tx] = (n < N_) ? f[((size_t)(b*C_ + c))*N_ + n] : 0.f;
  }
  __syncthreads();
  #pragma unroll
  for (int i = 0; i < 4; i++) {
    int n = n0 + ty + i*8, c = c0 + tx;
    if (n < N_) vf[((size_t)(b*N_ + n))*C_ + c] = f2bf(tile[tx][ty + i*8]);
  }
}

// ---------------- W_e[0:256][:], W_u -> transposed bf16 [Cout][K] ----------------
__global__ void k_transpose_w(const float* __restrict__ We, const float* __restrict__ Wu,
                              u16* __restrict__ WeT, u16* __restrict__ WuT) {
  __shared__ float tile[32][33];
  const float* src = blockIdx.z ? Wu : We;
  u16* dst = blockIdx.z ? WuT : WeT;
  int tx = threadIdx.x & 31, ty = threadIdx.x >> 5;
  int r0 = blockIdx.y * 32, c0 = blockIdx.x * 32;
  #pragma unroll
  for (int i = 0; i < 4; i++)
    tile[ty + i*8][tx] = src[(size_t)(r0 + ty + i*8)*C_ + c0 + tx];
  __syncthreads();
  #pragma unroll
  for (int i = 0; i < 4; i++)
    dst[(size_t)(c0 + ty + i*8)*C_ + r0 + tx] = f2bf(tile[tx][ty + i*8]);
}

// ---------------- histogram of dst ----------------
__global__ void k_hist(const int* __restrict__ edges, int* __restrict__ counts) {
  int i = blockIdx.x * 256 + threadIdx.x;
  if (i >= M_EDGE) return;
  int b = (i >= E_) ? 1 : 0;
  int e = i - b * E_;
  int d = edges[(size_t)(b*2 + 1)*E_ + e];
  atomicAdd(&counts[b*N_ + d], 1);
}

// ---------------- exclusive scan of PADDED counts (single block) ----------------
__global__ __launch_bounds__(1024)
void k_scan(const int* __restrict__ counts, int* __restrict__ offs, int* __restrict__ cursor) {
  __shared__ int part[1024];
  int t = threadIdx.x;
  int base = t * 20;
  int vals[20];
  if (t < 1000) {
    #pragma unroll
    for (int j = 0; j < 5; j++)
      *(int4*)&vals[j*4] = *(const int4*)&counts[base + j*4];
  } else {
    #pragma unroll
    for (int i = 0; i < 20; i++) vals[i] = 0;
  }
  int local[20];
  int s = 0;
  #pragma unroll
  for (int i = 0; i < 20; i++) {
    int pv = (vals[i] + 3) & ~3;          // pad each node to multiple of 4
    local[i] = s; s += pv;
  }
  part[t] = s;
  __syncthreads();
  for (int d = 1; d < 1024; d <<= 1) {
    int v = (t >= d) ? part[t - d] : 0;
    __syncthreads();
    part[t] += v;
    __syncthreads();
  }
  int excl = (t == 0) ? 0 : part[t - 1];
  if (t < 1000) {
    #pragma unroll
    for (int j = 0; j < 5; j++) {
      int4 o;
      o.x = excl + local[j*4 + 0];
      o.y = excl + local[j*4 + 1];
      o.z = excl + local[j*4 + 2];
      o.w = excl + local[j*4 + 3];
      *(int4*)&offs[base + j*4]   = o;
      *(int4*)&cursor[base + j*4] = o;
    }
  }
  if (t == 1023) offs[M_NODE] = part[1023];   // total padded size
}

// ---------------- scatter edges into padded CSR slots (packed 8B records) ----------------
// rec.x = f16(dx) | f16(dy)<<16 ; rec.y = f16(dz) | src_node<<16
__global__ void k_scatter(const int* __restrict__ edges, const float* __restrict__ xyz,
                          int* __restrict__ cursor, uint2* __restrict__ ed) {
  int i = blockIdx.x * 256 + threadIdx.x;
  if (i >= M_EDGE) return;
  int b = (i >= E_) ? 1 : 0;
  int e = i - b * E_;
  int s = edges[(size_t)(b*2 + 0)*E_ + e];
  int d = edges[(size_t)(b*2 + 1)*E_ + e];
  const float* ps = xyz + ((size_t)(b*N_ + s))*3;
  const float* pd = xyz + ((size_t)(b*N_ + d))*3;
  int pos = atomicAdd(&cursor[b*N_ + d], 1);
  u32 rx = (u32)f2h(ps[0]-pd[0]) | ((u32)f2h(ps[1]-pd[1]) << 16);
  u32 ry = (u32)f2h(ps[2]-pd[2]) | ((u32)(b*N_ + s) << 16);
  ed[pos] = make_uint2(rx, ry);
}

// ------- pad dup fill + tail fill + nodeInfo + waveStart table -------
// nodeInfo[n] = (paddedEnd << 10) | cnt
// waveStart[w] = first node whose padded segment starts >= w*SPW
__global__ void k_pad(const int* __restrict__ offs, const int* __restrict__ counts,
                      uint2* __restrict__ ed, u32* __restrict__ nodeInfo,
                      int* __restrict__ waveStart) {
  int i = blockIdx.x * 256 + threadIdx.x;
  const int T = offs[M_NODE];
  const int SPW = (T + NW_ - 1) / NW_;
  if (i < M_NODE) {
    int s = offs[i], e = offs[i+1];
    int cnt = counts[i];
    if (cnt > 0) {
      int pad = e - (s + cnt);
      if (pad) {
        uint2 f = ed[s];
        for (int k = 0; k < pad; k++) ed[s + cnt + k] = f;
      }
    }
    nodeInfo[i] = ((u32)e << 10) | (u32)cnt;
    int lo = (i == 0) ? 0 : offs[i-1] + 1;
    int wlo = (lo + SPW - 1) / SPW;
    int whi = offs[i] / SPW;
    for (int w = wlo; w <= whi && w <= NW_; w++) waveStart[w] = i;
  }
  if (i == M_NODE) {
    nodeInfo[M_NODE]   = ((u32)T << 10);
    nodeInfo[M_NODE+1] = ((u32)T << 10);
    int lo = offs[M_NODE-1] + 1;
    int wlo = (lo + SPW - 1) / SPW;
    if (wlo < 0) wlo = 0;
    for (int w = wlo; w <= NW_; w++) waveStart[w] = M_NODE;
  }
  int pos = T + i;
  if (pos < ED_CAP) ed[pos] = make_uint2(0u, 0u);   // tail: si=0, never stats-counted
}

// ---------------- z GEMM: z = vf @ We[0:256] + be (fp16 out) ----------------
__global__ __launch_bounds__(256)
void k_zgemm(const u16* __restrict__ A, const u16* __restrict__ WeT,
             const float* __restrict__ be, u16* __restrict__ zh)
{
  __shared__ __align__(16) u16 As[128*32];
  __shared__ __align__(16) u16 Bs[128*32];
  const int t  = threadIdx.x;
  const int n0 = blockIdx.x * 128;
  const int mb = blockIdx.y * 128;

  int r0 = mb + (t >> 2);      if (r0 >= M_NODE) r0 = 0;
  int r1 = mb + 64 + (t >> 2); if (r1 >= M_NODE) r1 = 0;
  const int ak = (((t & 3) ^ ((t >> 3) & 3)) << 3);
  const u16* asrc0 = A + (size_t)r0 * C_ + ak;
  const u16* asrc1 = A + (size_t)r1 * C_ + ak;
  const u16* bsrc0 = WeT + (size_t)(n0 + (t >> 2)) * C_ + ak;
  const u16* bsrc1 = WeT + (size_t)(n0 + 64 + (t >> 2)) * C_ + ak;

  const f32x4 zero = {0.f, 0.f, 0.f, 0.f};
  f32x4 acc[4][4];
  #pragma unroll
  for (int m = 0; m < 4; m++)
    #pragma unroll
    for (int n = 0; n < 4; n++) acc[m][n] = zero;

  const int lane = t & 63, wave = t >> 6;
  const int wr = wave >> 1, wc = wave & 1;
  const int lr = lane & 15, lch = lane >> 4;
  const int swz = (lr >> 1) & 3;

  for (int kk = 0; kk < 8; kk++) {
    const int k0 = kk * 32;
    async16(&As[t*8],        asrc0 + k0);
    async16(&As[(t+256)*8],  asrc1 + k0);
    async16(&Bs[t*8],        bsrc0 + k0);
    async16(&Bs[(t+256)*8],  bsrc1 + k0);
    __syncthreads();
    bf16x8 a[4], b[4];
    #pragma unroll
    for (int m = 0; m < 4; m++)
      a[m] = *(const bf16x8*)&As[(wr*64 + m*16 + lr)*32 + ((lch ^ swz) << 3)];
    #pragma unroll
    for (int n = 0; n < 4; n++)
      b[n] = *(const bf16x8*)&Bs[(wc*64 + n*16 + lr)*32 + ((lch ^ swz) << 3)];
    #pragma unroll
    for (int m = 0; m < 4; m++)
      #pragma unroll
      for (int n = 0; n < 4; n++)
        acc[m][n] = __builtin_amdgcn_mfma_f32_16x16x32_bf16(a[m], b[n], acc[m][n], 0, 0, 0);
    __syncthreads();
  }

  int gc[4]; float bias[4];
  #pragma unroll
  for (int n = 0; n < 4; n++) { int c = n0 + wc*64 + n*16 + lr; gc[n] = c; bias[n] = be[c]; }
  #pragma unroll
  for (int m = 0; m < 4; m++) {
    #pragma unroll
    for (int j = 0; j < 4; j++) {
      int r = mb + wr*64 + m*16 + lch*4 + j;
      if (r < M_NODE) {
        #pragma unroll
        for (int n = 0; n < 4; n++)
          zh[(size_t)r * C_ + gc[n]] = f2h(acc[m][n][j] + bias[n]);
      }
    }
  }
}

// -------- aggregation: channel-split (2 waves/stream), 2-ahead z pipeline --------
__global__ __launch_bounds__(512)
void k_agg(const u16* __restrict__ zh, const uint2* __restrict__ ed,
           const int* __restrict__ offs, const u32* __restrict__ nodeInfo,
           const int* __restrict__ waveStart,
           const float* __restrict__ We, const float* __restrict__ ge,
           u32* __restrict__ aggh, float* __restrict__ esum, float* __restrict__ esumsq)
{
  const int tid  = threadIdx.x;
  const int lane = tid & 63;
  const int wave = __builtin_amdgcn_readfirstlane(tid >> 6);   // 0..7, SGPR
  const int half = wave & 1;
  const int c0   = half * 128 + lane * 2;                      // 2 channels per lane
  h2 w0 = h2{(_Float16)We[256*C_ + c0], (_Float16)We[256*C_ + c0 + 1]};
  h2 w1 = h2{(_Float16)We[257*C_ + c0], (_Float16)We[257*C_ + c0 + 1]};
  h2 w2 = h2{(_Float16)We[258*C_ + c0], (_Float16)We[258*C_ + c0 + 1]};
  const float ge0 = ge[c0], ge1 = ge[c0 + 1];
  const u16* zp = zh + c0;

  float ps0 = 0.f, ps1 = 0.f, pq0 = 0.f, pq1 = 0.f;

  const int wid  = blockIdx.x * 4 + (wave >> 1);   // stream id, 8192 total
  int cur        = waveStart[wid];
  const int nEnd = waveStart[wid + 1];

  const h2 MXI = h2{(_Float16)-1.f, (_Float16)-1.f};
  const h2 MNI = h2{(_Float16)65504.f, (_Float16)65504.f};

  if (cur < nEnd) {
    const int slotBeg = offs[cur];
    const int slotEnd = offs[nEnd];
    if (slotEnd > slotBeg) {
      // skip leading empty nodes (zero padded length)
      u32 info = nodeInfo[cur];
      while ((int)(info >> 10) == slotBeg) { cur++; info = nodeInfo[cur]; }
      int curEnd   = (int)(info >> 10);
      int vE       = slotBeg + (int)(info & 1023u);
      u32 nextInfo = nodeInfo[cur + 1];

      h2 mx = MXI, mn = MNI;

      const uint2* edp = ed + slotBeg;
      const int nc = (slotEnd - slotBeg) >> 2;

      auto zld1 = [&](uint2 r) -> u32 {
        return *(const u32*)(zp + ((size_t)(r.y >> 16) << 8));
      };
      auto flush = [&](int node) {
        h2 s;
        s.x = (ge0 >= 0.f) ? mx.x : mn.x;
        s.y = (ge1 >= 0.f) ? mx.y : mn.y;
        aggh[(size_t)node * 128 + half * 64 + lane] = h22u(s);
      };
      auto processChunk = [&](int ci, const uint2 (&R)[4], const u32 (&Z)[4]) {
        const int slot = slotBeg + ci * 4;
        if (slot == curEnd) {                       // node boundary (chunk-aligned)
          flush(cur);
          mx = MXI; mn = MNI;
          cur++;
          u32 inf = nextInfo;
          while ((int)(inf >> 10) == curEnd) { cur++; inf = nodeInfo[cur]; }
          vE = curEnd + (int)(inf & 1023u);
          curEnd = (int)(inf >> 10);
          nextInfo = nodeInfo[cur + 1];
        }
        #pragma unroll
        for (int k = 0; k < 4; k++) {
          u32 rx = R[k].x, ry = R[k].y;
          h2 dxx = u2h2((rx & 0xffffu) | (rx << 16));
          h2 dyy = u2h2((rx >> 16) | (rx & 0xffff0000u));
          h2 dzz = u2h2((ry & 0xffffu) | (ry << 16));
          h2 y = dxx*w0 + dyy*w1 + dzz*w2 + u2h2(Z[k]);
          const h2 zero2 = h2{(_Float16)0.f, (_Float16)0.f};
          y = __builtin_elementwise_max(y, zero2);
          mx = __builtin_elementwise_max(mx, y);
          mn = __builtin_elementwise_min(mn, y);
          if (slot + k < vE) {                      // wave-uniform (exclude pad slots)
            float f0 = (float)y.x, f1 = (float)y.y;
            ps0 += f0; pq0 = fmaf(f0, f0, pq0);
            ps1 += f1; pq1 = fmaf(f1, f1, pq1);
          }
        }
      };

      // ---- 3-phase pipeline: records 3 chunks ahead, z issued 2 chunks ahead ----
      uint2 Ra[4], Rb[4], Rc[4];
      u32 Za[4], Zb[4];
      #pragma unroll
      for (int k = 0; k < 4; k++) Ra[k] = edp[k];
      #pragma unroll
      for (int k = 0; k < 4; k++) Rb[k] = edp[4 + k];
      #pragma unroll
      for (int k = 0; k < 4; k++) Rc[k] = edp[8 + k];
      #pragma unroll
      for (int k = 0; k < 4; k++) Za[k] = zld1(Ra[k]);
      #pragma unroll
      for (int k = 0; k < 4; k++) Zb[k] = zld1(Rb[k]);

      for (int i = 0; i < nc; i += 3) {
        u32 Zc[4];
        {
          #pragma unroll
          for (int k = 0; k < 4; k++) Zc[k] = zld1(Rc[k]);        // z(i+2), 2 ahead
          processChunk(i, Ra, Za);
          #pragma unroll
          for (int k = 0; k < 4; k++) Ra[k] = edp[(i+3)*4 + k];   // rec(i+3)
        }
        if (i + 1 < nc) {
          #pragma unroll
          for (int k = 0; k < 4; k++) Za[k] = zld1(Ra[k]);        // z(i+3), 2 ahead
          processChunk(i + 1, Rb, Zb);
          #pragma unroll
          for (int k = 0; k < 4; k++) Rb[k] = edp[(i+4)*4 + k];   // rec(i+4)
        }
        if (i + 2 < nc) {
          #pragma unroll
          for (int k = 0; k < 4; k++) Zb[k] = zld1(Rb[k]);        // z(i+4), 2 ahead
          processChunk(i + 2, Rc, Zc);
          #pragma unroll
          for (int k = 0; k < 4; k++) Rc[k] = edp[(i+5)*4 + k];   // rec(i+5)
        }
      }
      flush(cur);
    }
  }

  // block-level stats reduction: wave w covers channels [ (w&1)*128, +128 )
  __shared__ float red[8][256];
  red[wave][c0]     = ps0;
  red[wave][c0 + 1] = ps1;
  __syncthreads();
  if (tid < 256) {
    int base = (tid >= 128) ? 1 : 0;
    float s = red[base][tid] + red[base+2][tid] + red[base+4][tid] + red[base+6][tid];
    atomicAdd(&esum[tid], s);
  }
  __syncthreads();
  red[wave][c0]     = pq0;
  red[wave][c0 + 1] = pq1;
  __syncthreads();
  if (tid < 256) {
    int base = (tid >= 128) ? 1 : 0;
    float s = red[base][tid] + red[base+2][tid] + red[base+4][tid] + red[base+6][tid];
    atomicAdd(&esumsq[tid], s);
  }
}

// ---------------- BN stats -> scale/shift ----------------
__global__ void k_stats(const float* __restrict__ sum, const float* __restrict__ sumsq,
                        const float* __restrict__ g, const float* __restrict__ beta,
                        float cnt, float* __restrict__ scale, float* __restrict__ shift) {
  int c = threadIdx.x;
  float m = sum[c] / cnt;
  float v = sumsq[c] / cnt - m*m;
  v = fmaxf(v, 0.f);
  float s = g[c] * rsqrtf(v + EPS_);
  scale[c] = s;
  shift[c] = beta[c] - m*s;
}

// ---------------- agg (packed f16) -> normalized bf16 (empty segments -> 0) ----------------
__global__ void k_aggnorm(const u32* __restrict__ aggh, const int* __restrict__ counts,
                          const float* __restrict__ scale, const float* __restrict__ shift,
                          u32* __restrict__ out) {
  int i = blockIdx.x * 256 + threadIdx.x;       // u32 pair index
  if (i >= M_NODE*C_/2) return;
  int n = i >> 7;
  int p = (i & 127) * 2;                        // channel base
  int cnt = counts[n];
  h2 hv = u2h2(aggh[i]);
  float v0 = (cnt > 0) ? fmaf((float)hv.x, scale[p],   shift[p])   : 0.f;
  float v1 = (cnt > 0) ? fmaf((float)hv.y, scale[p+1], shift[p+1]) : 0.f;
  out[i] = ((u32)f2bf(v0)) | (((u32)f2bf(v1)) << 16);
}

// ---------------- u GEMM: y=relu(agg@Wu+b); stats; store y (bf16) ----------------
__global__ __launch_bounds__(256)
void k_ugemm(const u16* __restrict__ A, const u16* __restrict__ WuT,
             const float* __restrict__ bu,
             u16* __restrict__ yu, float* __restrict__ usum, float* __restrict__ usumsq)
{
  __shared__ __align__(16) u16 As[128*32];
  __shared__ __align__(16) u16 Bs[128*32];
  const int t  = threadIdx.x;
  const int n0 = blockIdx.x * 128;
  const int mb = blockIdx.y * 128;

  int r0 = mb + (t >> 2);      if (r0 >= M_NODE) r0 = 0;
  int r1 = mb + 64 + (t >> 2); if (r1 >= M_NODE) r1 = 0;
  const int ak = (((t & 3) ^ ((t >> 3) & 3)) << 3);
  const u16* asrc0 = A + (size_t)r0 * C_ + ak;
  const u16* asrc1 = A + (size_t)r1 * C_ + ak;
  const u16* bsrc0 = WuT + (size_t)(n0 + (t >> 2)) * C_ + ak;
  const u16* bsrc1 = WuT + (size_t)(n0 + 64 + (t >> 2)) * C_ + ak;

  const f32x4 zero = {0.f, 0.f, 0.f, 0.f};
  f32x4 acc[4][4];
  #pragma unroll
  for (int m = 0; m < 4; m++)
    #pragma unroll
    for (int n = 0; n < 4; n++) acc[m][n] = zero;

  const int lane = t & 63, wave = t >> 6;
  const int wr = wave >> 1, wc = wave & 1;
  const int lr = lane & 15, lch = lane >> 4;
  const int swz = (lr >> 1) & 3;

  for (int kk = 0; kk < 8; kk++) {
    const int k0 = kk * 32;
    async16(&As[t*8],        asrc0 + k0);
    async16(&As[(t+256)*8],  asrc1 + k0);
    async16(&Bs[t*8],        bsrc0 + k0);
    async16(&Bs[(t+256)*8],  bsrc1 + k0);
    __syncthreads();
    bf16x8 a[4], b[4];
    #pragma unroll
    for (int m = 0; m < 4; m++)
      a[m] = *(const bf16x8*)&As[(wr*64 + m*16 + lr)*32 + ((lch ^ swz) << 3)];
    #pragma unroll
    for (int n = 0; n < 4; n++)
      b[n] = *(const bf16x8*)&Bs[(wc*64 + n*16 + lr)*32 + ((lch ^ swz) << 3)];
    #pragma unroll
    for (int m = 0; m < 4; m++)
      #pragma unroll
      for (int n = 0; n < 4; n++)
        acc[m][n] = __builtin_amdgcn_mfma_f32_16x16x32_bf16(a[m], b[n], acc[m][n], 0, 0, 0);
    __syncthreads();
  }

  int gc[4]; float bias[4];
  #pragma unroll
  for (int n = 0; n < 4; n++) { int c = n0 + wc*64 + n*16 + lr; gc[n] = c; bias[n] = bu[c]; }
  float psum[4] = {0.f,0.f,0.f,0.f};
  float psq [4] = {0.f,0.f,0.f,0.f};
  #pragma unroll
  for (int m = 0; m < 4; m++) {
    #pragma unroll
    for (int j = 0; j < 4; j++) {
      int r = mb + wr*64 + m*16 + lch*4 + j;
      bool valid = r < M_NODE;
      #pragma unroll
      for (int n = 0; n < 4; n++) {
        float y = fmaxf(acc[m][n][j] + bias[n], 0.f);
        if (valid) {
          psum[n] += y;
          psq[n]  += y*y;
          yu[(size_t)r * C_ + gc[n]] = f2bf(y);
        }
      }
    }
  }
  #pragma unroll
  for (int n = 0; n < 4; n++) {
    float s1 = psum[n], s2 = psq[n];
    s1 += __shfl_xor(s1, 16, 64);  s2 += __shfl_xor(s2, 16, 64);
    s1 += __shfl_xor(s1, 32, 64);  s2 += __shfl_xor(s2, 32, 64);
    if (lch == 0) { atomicAdd(&usum[gc[n]], s1); atomicAdd(&usumsq[gc[n]], s2); }
  }
}

// -------- final: BN affine + residual (bf16 vf) + transpose to [B][C][N] --------
__global__ void k_final(const u16* __restrict__ yu, const u16* __restrict__ vf,
                        const float* __restrict__ scale, const float* __restrict__ shift,
                        float* __restrict__ out) {
  __shared__ float tile[32][33];
  int tx = threadIdx.x & 31, ty = threadIdx.x >> 5;
  int b = blockIdx.z, c0 = blockIdx.y * 32, n0 = blockIdx.x * 32;
  #pragma unroll
  for (int i = 0; i < 4; i++) {
    int n = n0 + ty + i*8, c = c0 + tx;
    float v = 0.f;
    if (n < N_) {
      size_t idx = ((size_t)(b*N_ + n))*C_ + c;
      v = bf2f(yu[idx]) * scale[c] + shift[c] + bf2f(vf[idx]);
    }
    tile[ty + i*8][tx] = v;
  }
  __syncthreads();
  int n = n0 + tx;
  if (n < N_) {
    #pragma unroll
    for (int i = 0; i < 4; i++) {
      int c = c0 + ty + i*8;
      out[((size_t)(b*C_ + c))*N_ + n] = tile[tx][ty + i*8];
    }
  }
}

extern "C" void kernel_launch(void* const* d_in, const int* in_sizes, int n_in,
                              void* d_out, int out_size, void* d_ws, size_t ws_size,
                              hipStream_t stream) {
  const float* xyz  = (const float*)d_in[0];
  const float* feat = (const float*)d_in[1];
  const int*   edges= (const int*)  d_in[2];
  const float* We   = (const float*)d_in[3];
  const float* be   = (const float*)d_in[4];
  const float* ge   = (const float*)d_in[5];
  const float* bte  = (const float*)d_in[6];
  const float* Wu   = (const float*)d_in[7];
  const float* bu   = (const float*)d_in[8];
  const float* gu   = (const float*)d_in[9];
  const float* btu  = (const float*)d_in[10];
  float* out = (float*)d_out;

  char* w = (char*)d_ws;
  size_t off = 0;
  auto carve = [&](size_t bytes) -> void* {
    void* p = w + off;
    off = (off + bytes + 511) & ~(size_t)511;
    return p;
  };
  u16*  vf       = (u16*) carve((size_t)M_NODE*C_*2);       // 10.24 MB
  u16*  WeT      = (u16*) carve((size_t)C_*C_*2);
  u16*  WuT      = (u16*) carve((size_t)C_*C_*2);
  u16*  zh       = (u16*) carve((size_t)M_NODE*C_*2);       // 10.24 MB (fp16)
  uint2* ed      = (uint2*)carve((size_t)ED_CAP*8);         // 2.9 MB
  int*  counts   = (int*) carve((size_t)M_NODE*4);
  int*  offs     = (int*) carve((size_t)(M_NODE+1)*4);
  int*  cursor   = (int*) carve((size_t)M_NODE*4);
  u32*  nodeInfo = (u32*) carve((size_t)(M_NODE+2)*4);
  int*  waveStart= (int*) carve((size_t)(NW_+1)*4);
  u32*  aggh     = (u32*) carve((size_t)M_NODE*128*4);      // 10.24 MB (packed f16)
  u32*  aggnorm  = (u32*) carve((size_t)M_NODE*C_*2);       // 10.24 MB (bf16)
  u16*  yu       = (u16*) carve((size_t)M_NODE*C_*2);       // 10.24 MB (bf16)
  float* stats   = (float*)carve(2048*4);
  float* esum = stats,        *esumsq = stats + 256;
  float* usum = stats + 512,  *usumsq = stats + 768;
  float* scale_e = stats + 1024, *shift_e = stats + 1280;
  float* scale_u = stats + 1536, *shift_u = stats + 1792;

  k_init<<<dim3((M_NODE + 255)/256), 256, 0, stream>>>(counts, stats);
  k_transpose_feat<<<dim3((N_+31)/32, C_/32, B_), 256, 0, stream>>>(feat, vf);
  k_transpose_w<<<dim3(C_/32, C_/32, 2), 256, 0, stream>>>(We, Wu, WeT, WuT);
  k_hist<<<dim3((M_EDGE + 255)/256), 256, 0, stream>>>(edges, counts);
  k_scan<<<1, 1024, 0, stream>>>(counts, offs, cursor);
  k_scatter<<<dim3((M_EDGE + 255)/256), 256, 0, stream>>>(edges, xyz, cursor, ed);
  k_pad<<<dim3((M_NODE + 255)/256), 256, 0, stream>>>(offs, counts, ed, nodeInfo, waveStart);
  k_zgemm<<<dim3(2, (M_NODE + 127)/128), 256, 0, stream>>>(vf, WeT, be, zh);
  k_agg<<<dim3(NW_/4), 512, 0, stream>>>(zh, ed, offs, nodeInfo, waveStart,
                                         We, ge, aggh, esum, esumsq);
  k_stats<<<1, 256, 0, stream>>>(esum, esumsq, ge, bte, (float)M_EDGE, scale_e, shift_e);
  k_aggnorm<<<dim3(M_NODE*C_/512), 256, 0, stream>>>(aggh, counts, scale_e, shift_e, aggnorm);
  k_ugemm<<<dim3(2, (M_NODE + 127)/128), 256, 0, stream>>>(
      (const u16*)aggnorm, WuT, bu, yu, usum, usumsq);
  k_stats<<<1, 256, 0, stream>>>(usum, usumsq, gu, btu, (float)M_NODE, scale_u, shift_u);
  k_final<<<dim3((N_+31)/32, C_/32, B_), 256, 0, stream>>>(yu, vf, scale_u, shift_u, out);
}